// Round 7
// baseline (3686.267 us; speedup 1.0000x reference)
//
#include <hip/hip_runtime.h>
#include <hip/hip_bf16.h>

using bf16 = __hip_bfloat16;
typedef __attribute__((ext_vector_type(8))) short bf16x8;   // 8 bf16 (4 VGPRs)
typedef __attribute__((ext_vector_type(4))) float f32x4;    // MFMA accumulator

constexpr int NN = 200000;   // nodes
constexpr int NE = 800000;   // edges
constexpr int NG = 4000;     // graphs
constexpr int ED = 16;       // edge feature dim
constexpr float BN_EPS = 1e-5f;

// ---------------- storage-type helpers (fp32 or bf16 node features) --------
__device__ __forceinline__ float  ld1(const float* p) { return *p; }
__device__ __forceinline__ float  ld1(const bf16*  p) { return __bfloat162float(*p); }
__device__ __forceinline__ float2 ld2f(const float* p) { return *(const float2*)p; }
__device__ __forceinline__ float2 ld2f(const bf16*  p) {
    union { ushort2 u; bf16 h[2]; } t;
    t.u = *(const ushort2*)p;
    return make_float2(__bfloat162float(t.h[0]), __bfloat162float(t.h[1]));
}
__device__ __forceinline__ float4 ld4(const float* p) { return *(const float4*)p; }
__device__ __forceinline__ float4 ld4(const bf16*  p) {
    union { ushort4 u; bf16 h[4]; } t;
    t.u = *(const ushort4*)p;
    return make_float4(__bfloat162float(t.h[0]), __bfloat162float(t.h[1]),
                       __bfloat162float(t.h[2]), __bfloat162float(t.h[3]));
}
__device__ __forceinline__ void st1(float* p, float v) { *p = v; }
__device__ __forceinline__ void st1(bf16*  p, float v) { *p = __float2bfloat16(v); }
__device__ __forceinline__ void st4(float* p, float4 v) { *(float4*)p = v; }
__device__ __forceinline__ void st4(bf16*  p, float4 v) {
    union { ushort4 u; bf16 h[4]; } t;
    t.h[0] = __float2bfloat16(v.x); t.h[1] = __float2bfloat16(v.y);
    t.h[2] = __float2bfloat16(v.z); t.h[3] = __float2bfloat16(v.w);
    *(ushort4*)p = t.u;
}

// ===========================================================================
// CSR-by-dst build (once per call; reused by all 3 conv layers)
// ===========================================================================
constexpr int SCAN_CHUNK = 1024;
constexpr int SCAN_NBLK  = (NN + SCAN_CHUNK - 1) / SCAN_CHUNK;   // 196

__global__ __launch_bounds__(256)
void k_hist(const int* __restrict__ ei, int* __restrict__ cnt)
{
    int e = blockIdx.x * 256 + threadIdx.x;
    const int stride = gridDim.x * 256;
    for (; e < NE; e += stride) atomicAdd(&cnt[ei[NE + e]], 1);
}

__global__ __launch_bounds__(256)
void k_scan_block(const int* __restrict__ cnt, int* __restrict__ bsum)
{
    __shared__ int red[256];
    const int b = blockIdx.x, t = threadIdx.x;
    const int base = b * SCAN_CHUNK + t * 4;
    int s = 0;
    #pragma unroll
    for (int k = 0; k < 4; ++k) { const int i = base + k; if (i < NN) s += cnt[i]; }
    red[t] = s; __syncthreads();
    for (int off = 128; off > 0; off >>= 1) {
        if (t < off) red[t] += red[t + off];
        __syncthreads();
    }
    if (t == 0) bsum[b] = red[0];
}

__global__ __launch_bounds__(256)
void k_scan_top(int* __restrict__ bsum, int n)
{
    __shared__ int sh[256];
    const int t = threadIdx.x;
    const int orig = (t < n) ? bsum[t] : 0;
    sh[t] = orig; __syncthreads();
    for (int off = 1; off < 256; off <<= 1) {
        const int v = (t >= off) ? sh[t - off] : 0;
        __syncthreads();
        sh[t] += v;
        __syncthreads();
    }
    if (t < n) bsum[t] = sh[t] - orig;   // exclusive
}

__global__ __launch_bounds__(256)
void k_scan_emit(const int* __restrict__ cnt, const int* __restrict__ bsum,
                 int* __restrict__ row_ptr, int* __restrict__ cursor)
{
    __shared__ int sh[256];
    const int b = blockIdx.x, t = threadIdx.x;
    const int base = b * SCAN_CHUNK + t * 4;
    int c[4]; int s = 0;
    #pragma unroll
    for (int k = 0; k < 4; ++k) {
        const int i = base + k;
        c[k] = (i < NN) ? cnt[i] : 0;    // read BEFORE aliased write below
        s += c[k];
    }
    const int orig = s;
    sh[t] = s; __syncthreads();
    for (int off = 1; off < 256; off <<= 1) {
        const int v = (t >= off) ? sh[t - off] : 0;
        __syncthreads();
        sh[t] += v;
        __syncthreads();
    }
    int run = bsum[b] + sh[t] - orig;     // exclusive prefix of this thread
    #pragma unroll
    for (int k = 0; k < 4; ++k) {
        const int i = base + k;
        if (i < NN) { row_ptr[i] = run; cursor[i] = run; run += c[k]; }
    }
    if (b == 0 && t == 0) row_ptr[NN] = NE;
}

// Fused scatter: place src id, dst id AND edge_attr row into perm order.
__global__ __launch_bounds__(256)
void k_scatter2(const int* __restrict__ ei, const float* __restrict__ ea,
                int* __restrict__ cursor, int* __restrict__ src_perm,
                int* __restrict__ dst_perm, float* __restrict__ ea_perm)
{
    int e = blockIdx.x * 256 + threadIdx.x;
    const int stride = gridDim.x * 256;
    for (; e < NE; e += stride) {
        const int d = ei[NE + e];
        const int p = atomicAdd(&cursor[d], 1);
        src_perm[p] = ei[e];
        dst_perm[p] = d;
        const float4* s = (const float4*)(ea + (size_t)e * ED);
        float4* t = (float4*)(ea_perm + (size_t)p * ED);
        t[0] = s[0]; t[1] = s[1]; t[2] = s[2]; t[3] = s[3];
    }
}

// One-shot: W[K,N] fp32 -> Wt[N,K] bf16 (transposed for the MFMA GEMM).
__global__ __launch_bounds__(256)
void k_wt(const float* __restrict__ W, bf16* __restrict__ Wt, int K, int N)
{
    const int i = blockIdx.x * 256 + threadIdx.x;
    if (i >= K * N) return;
    const int k = i / N, n = i % N;
    Wt[(size_t)n * K + k] = __float2bfloat16(W[i]);
}

// ===========================================================================
// Per-node aggregation v4: EDGE-PARALLEL with LDS fp32 accumulators.
// Block owns 32 consecutive dst nodes (edges contiguous in perm order).
// Waves stride over edges; fixed channel-half per wave -> We in VGPRs.
// LDS atomicAdd (ds_add_f32, no return) => no loop-carried dependency.
// agg[i] = x[i] + sum_{e: dst=i} relu(x[src_e] + ea_e@We + be), stored bf16.
// ===========================================================================
constexpr int NPB = 32;   // dst nodes per block

template<typename XT, int CIN>
__global__ __launch_bounds__(256)
void node_agg4(const XT* __restrict__ x, const float* __restrict__ ea_perm,
               const int* __restrict__ src_perm, const int* __restrict__ dst_perm,
               const int* __restrict__ row_ptr, const float* __restrict__ We,
               const float* __restrict__ be, bf16* __restrict__ agg)
{
    __shared__ float sacc[NPB * CIN];     // 16 KB (CIN=128) / 32 KB (CIN=256)
    const int tid  = threadIdx.x;
    const int lane = tid & 63;
    const int wave = tid >> 6;
    const int n0   = blockIdx.x * NPB;

    // channel/edge assignment: CIN=128 -> all 4 waves same channels, stride 4
    //                          CIN=256 -> waves {0,1}/{2,3} = halves, stride 2
    const int half    = (CIN == 128) ? 0 : (wave & 1);
    const int eoff    = (CIN == 128) ? wave : (wave >> 1);
    const int estride = (CIN == 128) ? 4 : 2;
    const int c0      = half * 128 + lane * 2;

    // This wave's We columns + bias -> registers (loaded once).
    float w0[ED], w1[ED];
    #pragma unroll
    for (int k = 0; k < ED; ++k) {
        w0[k] = We[k * CIN + c0];
        w1[k] = We[k * CIN + c0 + 1];
    }
    const float b0 = be[c0], b1 = be[c0 + 1];

    // init LDS acc with self term x_i (coalesced 4-wide)
    for (int i = tid * 4; i < NPB * CIN; i += 1024) {
        const float4 v = ld4(&x[(size_t)n0 * CIN + i]);
        *(float4*)&sacc[i] = v;
    }
    const int e_begin = row_ptr[n0];
    const int e_end   = row_ptr[n0 + NPB];
    __syncthreads();

    for (int idx = e_begin + eoff; idx < e_end; idx += estride) {
        const int src  = src_perm[idx];
        const int dstl = dst_perm[idx] - n0;
        const float* ep = ea_perm + (size_t)idx * ED;
        float ev[ED];
        *(float4*)&ev[0]  = *(const float4*)(ep + 0);
        *(float4*)&ev[4]  = *(const float4*)(ep + 4);
        *(float4*)&ev[8]  = *(const float4*)(ep + 8);
        *(float4*)&ev[12] = *(const float4*)(ep + 12);
        const float2 xv = ld2f(&x[(size_t)src * CIN + c0]);
        float m0 = b0, m1 = b1;
        #pragma unroll
        for (int k = 0; k < ED; ++k) {
            m0 = fmaf(ev[k], w0[k], m0);
            m1 = fmaf(ev[k], w1[k], m1);
        }
        m0 = fmaxf(m0 + xv.x, 0.f);
        m1 = fmaxf(m1 + xv.y, 0.f);
        atomicAdd(&sacc[dstl * CIN + c0], m0);       // ds_add_f32, no return
        atomicAdd(&sacc[dstl * CIN + c0 + 1], m1);
    }
    __syncthreads();

    // write back bf16 (coalesced ushort4)
    for (int i = tid * 4; i < NPB * CIN; i += 1024) {
        const float4 v = *(const float4*)&sacc[i];
        st4(&agg[(size_t)n0 * CIN + i], v);
    }
}

// ===========================================================================
// MFMA GEMM for conv layers: C[M,256] = relu(A[M,K] @ Wt[256,K]^T + bias)
// A bf16 row-major, Wt bf16 [N,K] (pre-transposed), C bf16, fp32 accumulate.
// 128x128 tile, BK=32, 256 threads = 4 waves (each 64x64), 16x16x32 MFMA.
// ===========================================================================
template<int K>
__global__ __launch_bounds__(256)
void gemm_mfma(const bf16* __restrict__ A, const bf16* __restrict__ Wt,
               const float* __restrict__ bias, bf16* __restrict__ C, int M)
{
    constexpr int LDT = 40;                 // padded LDS row stride (bf16)
    __shared__ short As[128 * LDT];
    __shared__ short Bs[128 * LDT];
    const int tid  = threadIdx.x;
    const int bm   = blockIdx.y * 128;
    const int bn   = blockIdx.x * 128;      // 0 or 128 (N = 256)
    const int lane = tid & 63;
    const int wave = tid >> 6;
    const int wr   = (wave >> 1) * 64;      // wave row offset in tile
    const int wc   = (wave & 1) * 64;       // wave col offset
    const int l15  = lane & 15;
    const int quad = lane >> 4;

    f32x4 acc[4][4];
    #pragma unroll
    for (int i = 0; i < 4; ++i)
        #pragma unroll
        for (int j = 0; j < 4; ++j)
            acc[i][j] = (f32x4){0.f, 0.f, 0.f, 0.f};

    for (int k0 = 0; k0 < K; k0 += 32) {
        #pragma unroll
        for (int c = tid; c < 512; c += 256) {
            const int row = c >> 2, part = c & 3;
            int ar = bm + row; if (ar >= M) ar = M - 1;   // clamp; rows discarded at store
            *(ulonglong2*)&As[row * LDT + part * 8] =
                *(const ulonglong2*)&A[(size_t)ar * K + k0 + part * 8];
            *(ulonglong2*)&Bs[row * LDT + part * 8] =
                *(const ulonglong2*)&Wt[(size_t)(bn + row) * K + k0 + part * 8];
        }
        __syncthreads();

        bf16x8 af[4], bfr[4];
        #pragma unroll
        for (int i = 0; i < 4; ++i) {
            af[i]  = *(const bf16x8*)&As[(wr + i * 16 + l15) * LDT + quad * 8];
            bfr[i] = *(const bf16x8*)&Bs[(wc + i * 16 + l15) * LDT + quad * 8];
        }
        #pragma unroll
        for (int mi = 0; mi < 4; ++mi)
            #pragma unroll
            for (int ni = 0; ni < 4; ++ni)
                acc[mi][ni] = __builtin_amdgcn_mfma_f32_16x16x32_bf16(
                                  af[mi], bfr[ni], acc[mi][ni], 0, 0, 0);
        __syncthreads();
    }

    // epilogue: D row = quad*4+reg, col = lane&15 (m89-verified C/D layout)
    float bv[4];
    #pragma unroll
    for (int ni = 0; ni < 4; ++ni)
        bv[ni] = bias[bn + wc + ni * 16 + l15];
    #pragma unroll
    for (int mi = 0; mi < 4; ++mi) {
        const int row0 = bm + wr + mi * 16 + quad * 4;
        #pragma unroll
        for (int r = 0; r < 4; ++r) {
            const int row = row0 + r;
            if (row < M) {
                #pragma unroll
                for (int ni = 0; ni < 4; ++ni) {
                    float v = acc[mi][ni][r] + bv[ni];
                    v = fmaxf(v, 0.f);
                    C[(size_t)row * 256 + bn + wc + ni * 16 + l15] = __float2bfloat16(v);
                }
            }
        }
    }
}

// ---------------------------------------------------------------------------
// fp32 GEMM (dense head only): C = (relu?)(A @ W + bias)
// ---------------------------------------------------------------------------
template<bool RELU, typename InT, typename OutT>
__global__ __launch_bounds__(256)
void gemm_rk(const InT* __restrict__ A, const float* __restrict__ W,
             const float* __restrict__ bias, OutT* __restrict__ C,
             int M, int N, int K)
{
    __shared__ float Asm[16][64];
    __shared__ float Wsm[16][64];
    const int bm = blockIdx.y * 64;
    const int bn = blockIdx.x * 64;
    const int tid = threadIdx.x;
    const int tx = tid & 15, ty = tid >> 4;
    const int ar = tid >> 2, ac = (tid & 3) * 4;
    const int wrr = tid >> 4, wcc = (tid & 15) * 4;

    float acc[4][4] = {};

    for (int k0 = 0; k0 < K; k0 += 16) {
        float4 av = make_float4(0.f, 0.f, 0.f, 0.f);
        if (bm + ar < M)
            av = ld4(A + (size_t)(bm + ar) * K + k0 + ac);
        Asm[ac + 0][ar] = av.x; Asm[ac + 1][ar] = av.y;
        Asm[ac + 2][ar] = av.z; Asm[ac + 3][ar] = av.w;

        float4 wv = make_float4(0.f, 0.f, 0.f, 0.f);
        if (bn + wcc < N)
            wv = *(const float4*)(W + (size_t)(k0 + wrr) * N + bn + wcc);
        *(float4*)&Wsm[wrr][wcc] = wv;
        __syncthreads();

        #pragma unroll
        for (int k = 0; k < 16; ++k) {
            const float4 a4 = *(const float4*)&Asm[k][ty * 4];
            const float4 b4 = *(const float4*)&Wsm[k][tx * 4];
            const float aa[4] = {a4.x, a4.y, a4.z, a4.w};
            const float bb[4] = {b4.x, b4.y, b4.z, b4.w};
            #pragma unroll
            for (int i = 0; i < 4; ++i)
                #pragma unroll
                for (int j = 0; j < 4; ++j)
                    acc[i][j] += aa[i] * bb[j];
        }
        __syncthreads();
    }

    float bvals[4];
    #pragma unroll
    for (int j = 0; j < 4; ++j) {
        const int col = bn + tx * 4 + j;
        bvals[j] = (col < N) ? bias[col] : 0.f;
    }
    #pragma unroll
    for (int i = 0; i < 4; ++i) {
        const int row = bm + ty * 4 + i;
        if (row >= M) continue;
        float v[4];
        #pragma unroll
        for (int j = 0; j < 4; ++j) {
            v[j] = acc[i][j] + bvals[j];
            if (RELU) v[j] = fmaxf(v[j], 0.f);
        }
        if (bn + tx * 4 + 3 < N) {
            st4(C + (size_t)row * N + bn + tx * 4, make_float4(v[0], v[1], v[2], v[3]));
        } else {
            #pragma unroll
            for (int j = 0; j < 4; ++j) {
                const int col = bn + tx * 4 + j;
                if (col < N) st1(C + (size_t)row * N + col, v[j]);
            }
        }
    }
}

// ---------------------------------------------------------------------------
// BatchNorm stats + normalize (bf16 H), fp32 accumulate.
// ---------------------------------------------------------------------------
template<typename InT>
__global__ __launch_bounds__(256)
void bn_stats(const InT* __restrict__ h, float* __restrict__ stats, int nodes)
{
    const int c = threadIdx.x;
    size_t n0 = (size_t)blockIdx.x * 128;
    size_t n1 = n0 + 128; if (n1 > (size_t)nodes) n1 = nodes;
    if (n0 >= (size_t)nodes) return;
    float s = 0.f, s2 = 0.f;
    for (size_t n = n0; n < n1; ++n) {
        const float v = ld1(&h[n * 256 + c]);
        s += v; s2 += v * v;
    }
    atomicAdd(&stats[c], s);
    atomicAdd(&stats[256 + c], s2);
}

template<typename T>
__global__ __launch_bounds__(256)
void bn_norm(T* __restrict__ h, const float* __restrict__ stats,
             const float* __restrict__ gamma, const float* __restrict__ beta, int n4)
{
    int i = blockIdx.x * 256 + threadIdx.x;
    const int stride = gridDim.x * 256;
    const float inv = 1.f / (float)NN;
    for (; i < n4; i += stride) {
        const int c = (i * 4) & 255;
        float4 v  = ld4(h + (size_t)i * 4);
        const float4 s  = *(const float4*)&stats[c];
        const float4 s2 = *(const float4*)&stats[256 + c];
        const float4 g  = *(const float4*)&gamma[c];
        const float4 b  = *(const float4*)&beta[c];
        float mu, sc;
        mu = s.x * inv; sc = rsqrtf(s2.x * inv - mu * mu + BN_EPS) * g.x; v.x = (v.x - mu) * sc + b.x;
        mu = s.y * inv; sc = rsqrtf(s2.y * inv - mu * mu + BN_EPS) * g.y; v.y = (v.y - mu) * sc + b.y;
        mu = s.z * inv; sc = rsqrtf(s2.z * inv - mu * mu + BN_EPS) * g.z; v.z = (v.z - mu) * sc + b.z;
        mu = s.w * inv; sc = rsqrtf(s2.w * inv - mu * mu + BN_EPS) * g.w; v.w = (v.w - mu) * sc + b.w;
        st4(h + (size_t)i * 4, v);
    }
}

// ---------------------------------------------------------------------------
// Mean-pool over sorted batch ids.
// ---------------------------------------------------------------------------
template<typename InT>
__global__ __launch_bounds__(256)
void pool_sum(const InT* __restrict__ h, const int* __restrict__ batch,
              float* __restrict__ sums, float* __restrict__ cnts)
{
    const int c = threadIdx.x;
    size_t n0 = (size_t)blockIdx.x * 128;
    size_t n1 = n0 + 128; if (n1 > (size_t)NN) n1 = NN;
    if (n0 >= (size_t)NN) return;
    int cur = batch[n0];
    float s = 0.f, cnt = 0.f;
    for (size_t n = n0; n < n1; ++n) {
        const int b = batch[n];
        if (b != cur) {
            atomicAdd(&sums[(size_t)cur * 256 + c], s);
            if (c == 0) atomicAdd(&cnts[cur], cnt);
            s = 0.f; cnt = 0.f; cur = b;
        }
        s += ld1(&h[n * 256 + c]);
        cnt += 1.f;
    }
    atomicAdd(&sums[(size_t)cur * 256 + c], s);
    if (c == 0) atomicAdd(&cnts[cur], cnt);
}

__global__ __launch_bounds__(256)
void pool_div(float* __restrict__ sums, const float* __restrict__ cnts)
{
    const int i = blockIdx.x * 256 + threadIdx.x;   // NG*256 threads exactly
    const int g = i >> 8;
    sums[i] = sums[i] / fmaxf(cnts[g], 1.f);
}

__global__ __launch_bounds__(256)
void head_out(const float* __restrict__ y, const float* __restrict__ Wo,
              const float* __restrict__ bo, float* __restrict__ out)
{
    const int g = blockIdx.x * 256 + threadIdx.x;
    if (g >= NG) return;
    float s = bo[0];
    #pragma unroll
    for (int k = 0; k < 32; ++k) s += y[g * 32 + k] * Wo[k];
    out[g] = s;
}

__global__ __launch_bounds__(256)
void diag_fill(float* __restrict__ out, int n, float v)
{
    const int i = blockIdx.x * 256 + threadIdx.x;
    if (i < n) out[i] = v;
}

// ---------------------------------------------------------------------------
extern "C" void kernel_launch(void* const* d_in, const int* in_sizes, int n_in,
                              void* d_out, int out_size, void* d_ws, size_t ws_size,
                              hipStream_t stream)
{
    const float* x    = (const float*)d_in[0];
    const int*   ei   = (const int*)d_in[1];
    const int*   batch= (const int*)d_in[2];
    const float* ea   = (const float*)d_in[3];
    const float* We[3] = {(const float*)d_in[4],  (const float*)d_in[10], (const float*)d_in[16]};
    const float* be[3] = {(const float*)d_in[5],  (const float*)d_in[11], (const float*)d_in[17]};
    const float* Wn[3] = {(const float*)d_in[6],  (const float*)d_in[12], (const float*)d_in[18]};
    const float* bnb[3]= {(const float*)d_in[7],  (const float*)d_in[13], (const float*)d_in[19]};
    const float* gm[3] = {(const float*)d_in[8],  (const float*)d_in[14], (const float*)d_in[20]};
    const float* bt[3] = {(const float*)d_in[9],  (const float*)d_in[15], (const float*)d_in[21]};
    const float* Wd0 = (const float*)d_in[22]; const float* bd0 = (const float*)d_in[23];
    const float* Wd1 = (const float*)d_in[24]; const float* bd1 = (const float*)d_in[25];
    const float* Wd2 = (const float*)d_in[26]; const float* bd2 = (const float*)d_in[27];
    const float* Wo  = (const float*)d_in[28]; const float* bo  = (const float*)d_in[29];
    float* out = (float*)d_out;
    float* ws  = (float*)d_ws;

    // ---- workspace layout (float offsets; 16B alignment kept) ----
    bf16*  H        = (bf16*)ws;                  // NN*256 bf16 = 25.6M fl
    bf16*  AGG      = (bf16*)(ws + 25600000);     // NN*256 bf16 = 25.6M fl
    float* st       = ws + 51200000;              // 512 fl
    bf16*  wt0      = (bf16*)(ws + 51200512);     // 128*256 bf16 = 16384 fl
    bf16*  wt1      = wt0 + 32768;                // 256*256 bf16 = 32768 fl
    bf16*  wt2      = wt1 + 65536;                // 256*256 bf16 = 32768 fl
    float* ea_perm  = ws + 51282432;              // NE*16 fp32 = 12.8M fl
    int*   src_perm = (int*)(ws + 64082432);      // NE
    int*   dst_perm = src_perm + NE;              // NE
    int*   row_ptr  = dst_perm + NE;              // NN+1
    int*   cursor   = row_ptr + (NN + 1);         // NN
    int*   bsum     = cursor + NN;                // SCAN_NBLK
    const size_t NEED = (size_t)(64082432 + NE + NE + (NN + 1) + NN + SCAN_NBLK) * 4;

    if (ws_size < NEED) {
        diag_fill<<<(NG + 255) / 256, 256, 0, stream>>>(out, NG, (float)(ws_size >> 20));
        return;
    }

    // ---- one-time prep: CSR build + fused edge scatter, weight transpose ----
    hipMemsetAsync(row_ptr, 0, (size_t)(NN + 1) * 4, stream);
    k_hist<<<1024, 256, 0, stream>>>(ei, row_ptr);
    k_scan_block<<<SCAN_NBLK, 256, 0, stream>>>(row_ptr, bsum);
    k_scan_top<<<1, 256, 0, stream>>>(bsum, SCAN_NBLK);
    k_scan_emit<<<SCAN_NBLK, 256, 0, stream>>>(row_ptr, bsum, row_ptr, cursor);
    k_scatter2<<<1024, 256, 0, stream>>>(ei, ea, cursor, src_perm, dst_perm, ea_perm);
    k_wt<<<(128 * 256 + 255) / 256, 256, 0, stream>>>(Wn[0], wt0, 128, 256);
    k_wt<<<(256 * 256 + 255) / 256, 256, 0, stream>>>(Wn[1], wt1, 256, 256);
    k_wt<<<(256 * 256 + 255) / 256, 256, 0, stream>>>(Wn[2], wt2, 256, 256);

    const dim3 mfma_grid(2, (NN + 127) / 128);    // N=256 -> 2 col-blocks
    const int  agg_grid = NN / NPB;               // 6250 blocks (NN % 32 == 0)

    // ---- layer 0 (cin=128 -> 256), input x fp32 ----
    node_agg4<float, 128><<<agg_grid, 256, 0, stream>>>(x, ea_perm, src_perm, dst_perm, row_ptr, We[0], be[0], AGG);
    gemm_mfma<128><<<mfma_grid, 256, 0, stream>>>(AGG, wt0, bnb[0], H, NN);
    hipMemsetAsync(st, 0, 512 * 4, stream);
    bn_stats<bf16><<<(NN + 127) / 128, 256, 0, stream>>>(H, st, NN);
    bn_norm<bf16><<<2048, 256, 0, stream>>>(H, st, gm[0], bt[0], NN * 256 / 4);

    // ---- layers 1,2 (256 -> 256), input H bf16 ----
    for (int l = 1; l < 3; ++l) {
        node_agg4<bf16, 256><<<agg_grid, 256, 0, stream>>>(H, ea_perm, src_perm, dst_perm, row_ptr, We[l], be[l], AGG);
        gemm_mfma<256><<<mfma_grid, 256, 0, stream>>>(AGG, (l == 1) ? wt1 : wt2, bnb[l], H, NN);
        hipMemsetAsync(st, 0, 512 * 4, stream);
        bn_stats<bf16><<<(NN + 127) / 128, 256, 0, stream>>>(H, st, NN);
        bn_norm<bf16><<<2048, 256, 0, stream>>>(H, st, gm[l], bt[l], NN * 256 / 4);
    }

    // ---- head scratch overlays AGG (dead after last conv GEMM) ----
    float* poolb = (float*)AGG;           // NG*256 = 1,024,000 fl
    float* cnts  = poolb + 1024000;       // NG
    float* y1    = poolb + 1028000;       // NG*512
    float* y2    = poolb + 3076000;       // NG*128
    float* y3    = poolb + 3588000;       // NG*32

    hipMemsetAsync(poolb, 0, (size_t)NG * 256 * 4, stream);
    hipMemsetAsync(cnts, 0, (size_t)NG * 4, stream);
    pool_sum<bf16><<<(NN + 127) / 128, 256, 0, stream>>>(H, batch, poolb, cnts);
    pool_div<<<NG, 256, 0, stream>>>(poolb, cnts);

    // ---- dense head (fp32) ----
    gemm_rk<true, float, float><<<dim3(8, (NG + 63) / 64), 256, 0, stream>>>(poolb, Wd0, bd0, y1, NG, 512, 256);
    gemm_rk<true, float, float><<<dim3(2, (NG + 63) / 64), 256, 0, stream>>>(y1, Wd1, bd1, y2, NG, 128, 512);
    gemm_rk<true, float, float><<<dim3(1, (NG + 63) / 64), 256, 0, stream>>>(y2, Wd2, bd2, y3, NG, 32, 128);
    head_out<<<(NG + 255) / 256, 256, 0, stream>>>(y3, Wo, bo, out);
}

// Round 8
// 3658.950 us; speedup vs baseline: 1.0075x; 1.0075x over previous
//
#include <hip/hip_runtime.h>
#include <hip/hip_bf16.h>

using bf16 = __hip_bfloat16;
typedef __attribute__((ext_vector_type(8))) short bf16x8;   // 8 bf16 (4 VGPRs)
typedef __attribute__((ext_vector_type(4))) float f32x4;    // MFMA accumulator

constexpr int NN = 200000;   // nodes
constexpr int NE = 800000;   // edges
constexpr int NG = 4000;     // graphs
constexpr int ED = 16;       // edge feature dim
constexpr float BN_EPS = 1e-5f;

// ---------------- storage-type helpers (fp32 or bf16 node features) --------
__device__ __forceinline__ float  ld1(const float* p) { return *p; }
__device__ __forceinline__ float  ld1(const bf16*  p) { return __bfloat162float(*p); }
__device__ __forceinline__ float4 ld4(const float* p) { return *(const float4*)p; }
__device__ __forceinline__ float4 ld4(const bf16*  p) {
    union { ushort4 u; bf16 h[4]; } t;
    t.u = *(const ushort4*)p;
    return make_float4(__bfloat162float(t.h[0]), __bfloat162float(t.h[1]),
                       __bfloat162float(t.h[2]), __bfloat162float(t.h[3]));
}
__device__ __forceinline__ void st1(float* p, float v) { *p = v; }
__device__ __forceinline__ void st1(bf16*  p, float v) { *p = __float2bfloat16(v); }
__device__ __forceinline__ void st4(float* p, float4 v) { *(float4*)p = v; }
__device__ __forceinline__ void st4(bf16*  p, float4 v) {
    union { ushort4 u; bf16 h[4]; } t;
    t.h[0] = __float2bfloat16(v.x); t.h[1] = __float2bfloat16(v.y);
    t.h[2] = __float2bfloat16(v.z); t.h[3] = __float2bfloat16(v.w);
    *(ushort4*)p = t.u;
}

// ===========================================================================
// CSR-by-dst build (once per call; reused by all 3 conv layers)
// ===========================================================================
constexpr int SCAN_CHUNK = 1024;
constexpr int SCAN_NBLK  = (NN + SCAN_CHUNK - 1) / SCAN_CHUNK;   // 196

__global__ __launch_bounds__(256)
void k_hist(const int* __restrict__ ei, int* __restrict__ cnt)
{
    int e = blockIdx.x * 256 + threadIdx.x;
    const int stride = gridDim.x * 256;
    for (; e < NE; e += stride) atomicAdd(&cnt[ei[NE + e]], 1);
}

__global__ __launch_bounds__(256)
void k_scan_block(const int* __restrict__ cnt, int* __restrict__ bsum)
{
    __shared__ int red[256];
    const int b = blockIdx.x, t = threadIdx.x;
    const int base = b * SCAN_CHUNK + t * 4;
    int s = 0;
    #pragma unroll
    for (int k = 0; k < 4; ++k) { const int i = base + k; if (i < NN) s += cnt[i]; }
    red[t] = s; __syncthreads();
    for (int off = 128; off > 0; off >>= 1) {
        if (t < off) red[t] += red[t + off];
        __syncthreads();
    }
    if (t == 0) bsum[b] = red[0];
}

__global__ __launch_bounds__(256)
void k_scan_top(int* __restrict__ bsum, int n)
{
    __shared__ int sh[256];
    const int t = threadIdx.x;
    const int orig = (t < n) ? bsum[t] : 0;
    sh[t] = orig; __syncthreads();
    for (int off = 1; off < 256; off <<= 1) {
        const int v = (t >= off) ? sh[t - off] : 0;
        __syncthreads();
        sh[t] += v;
        __syncthreads();
    }
    if (t < n) bsum[t] = sh[t] - orig;   // exclusive
}

__global__ __launch_bounds__(256)
void k_scan_emit(const int* __restrict__ cnt, const int* __restrict__ bsum,
                 int* __restrict__ row_ptr, int* __restrict__ cursor)
{
    __shared__ int sh[256];
    const int b = blockIdx.x, t = threadIdx.x;
    const int base = b * SCAN_CHUNK + t * 4;
    int c[4]; int s = 0;
    #pragma unroll
    for (int k = 0; k < 4; ++k) {
        const int i = base + k;
        c[k] = (i < NN) ? cnt[i] : 0;    // read BEFORE aliased write below
        s += c[k];
    }
    const int orig = s;
    sh[t] = s; __syncthreads();
    for (int off = 1; off < 256; off <<= 1) {
        const int v = (t >= off) ? sh[t - off] : 0;
        __syncthreads();
        sh[t] += v;
        __syncthreads();
    }
    int run = bsum[b] + sh[t] - orig;     // exclusive prefix of this thread
    #pragma unroll
    for (int k = 0; k < 4; ++k) {
        const int i = base + k;
        if (i < NN) { row_ptr[i] = run; cursor[i] = run; run += c[k]; }
    }
    if (b == 0 && t == 0) row_ptr[NN] = NE;
}

// Fused scatter: src id, dst id, edge_attr row (converted bf16) -> perm order.
__global__ __launch_bounds__(256)
void k_scatter2(const int* __restrict__ ei, const float* __restrict__ ea,
                int* __restrict__ cursor, int* __restrict__ src_perm,
                int* __restrict__ dst_perm, bf16* __restrict__ ea_perm)
{
    int e = blockIdx.x * 256 + threadIdx.x;
    const int stride = gridDim.x * 256;
    for (; e < NE; e += stride) {
        const int d = ei[NE + e];
        const int p = atomicAdd(&cursor[d], 1);
        src_perm[p] = ei[e];
        dst_perm[p] = d;
        const float4* s = (const float4*)(ea + (size_t)e * ED);
        #pragma unroll
        for (int q = 0; q < 4; ++q)
            st4(ea_perm + (size_t)p * ED + q * 4, s[q]);
    }
}

// One-shot: W[K,N] fp32 -> Wt[N,K] bf16 (transposed for the MFMA GEMM).
__global__ __launch_bounds__(256)
void k_wt(const float* __restrict__ W, bf16* __restrict__ Wt, int K, int N)
{
    const int i = blockIdx.x * 256 + threadIdx.x;
    if (i >= K * N) return;
    const int k = i / N, n = i % N;
    Wt[(size_t)n * K + k] = __float2bfloat16(W[i]);
}

// One-shot: pack We[16,CIN] into B-operand fragments for 16x16x32 MFMA with
// K=32 zero-padded (k>=16 -> 0). Wb[(nbg*64+lane)*8 + j] = We[quad*8+j][nbg*16+l15].
__global__ __launch_bounds__(256)
void k_wb(const float* __restrict__ We, bf16* __restrict__ Wb, int CIN)
{
    const int t = blockIdx.x * 256 + threadIdx.x;    // over (CIN/16)*64
    if (t >= CIN * 4) return;
    const int lane = t & 63, nbg = t >> 6;
    const int l15 = lane & 15, quad = lane >> 4;
    const int col = nbg * 16 + l15;
    #pragma unroll
    for (int j = 0; j < 8; ++j) {
        const int k = quad * 8 + j;
        Wb[(size_t)t * 8 + j] = __float2bfloat16((k < ED) ? We[k * CIN + col] : 0.f);
    }
}

// ===========================================================================
// Per-node aggregation v5: node-range blocks + MFMA edge-MLP + LDS fp32 acc.
// Block owns 32 consecutive dst nodes (perm is dst-sorted -> contiguous edges).
// Edges processed in 16-edge MFMA groups: A = ea rows (K=32, top half zero),
// B = pre-packed We fragments, C init = bias. Epilogue per lane: 4 rows x 1
// col: + x[src] gather, relu, ds_add into sacc. Writeback bf16, coalesced.
// ===========================================================================
constexpr int NPB = 32;   // dst nodes per block

template<typename XT, int CIN>
__global__ __launch_bounds__(256)
void node_agg5(const XT* __restrict__ x, const bf16* __restrict__ ea_perm,
               const int* __restrict__ src_perm, const int* __restrict__ dst_perm,
               const int* __restrict__ row_ptr, const bf16* __restrict__ Wb,
               const float* __restrict__ be, bf16* __restrict__ agg)
{
    constexpr int LDSROW = CIN + 4;            // pad: de-alias quad banks
    __shared__ float sacc[NPB * LDSROW];       // ~16.5/33 KB
    const int tid = threadIdx.x, lane = tid & 63, wave = tid >> 6;
    const int l15 = lane & 15, quad = lane >> 4;
    constexpr int WCOL  = CIN / 64;            // waves covering the channels
    constexpr int ESTEP = 4 / WCOL;            // wave-groups striding edge chunks
    const int colw = (wave % WCOL) * 64;
    const int eoff = wave / WCOL;
    const int n0 = blockIdx.x * NPB;

    // B fragments (4 x 16-col blocks per wave) + bias, loaded once.
    bf16x8 bfr[4];
    float  bev[4];
    #pragma unroll
    for (int nb = 0; nb < 4; ++nb) {
        const int nbg = (colw >> 4) + nb;
        bfr[nb] = *(const bf16x8*)&Wb[(size_t)(nbg * 64 + lane) * 8];
        bev[nb] = be[colw + nb * 16 + l15];
    }

    // init LDS acc with self term x_i (coalesced)
    for (int i = tid * 4; i < NPB * CIN; i += 1024) {
        const int node = i / CIN, col = i % CIN;
        *(float4*)&sacc[node * LDSROW + col] = ld4(&x[(size_t)n0 * CIN + i]);
    }
    const int e_begin = row_ptr[n0];
    const int e_end   = row_ptr[n0 + NPB];
    __syncthreads();

    for (int e0 = e_begin + eoff * 32; e0 < e_end; e0 += ESTEP * 32) {
        #pragma unroll
        for (int g = 0; g < 2; ++g) {
            const int ebase = e0 + g * 16;          // wave-uniform
            if (ebase >= e_end) break;
            // A fragment: m = l15, k = quad*8+j (quads 2,3 -> zero pad)
            bf16x8 afr = {};
            if (quad < 2) {
                int ae = ebase + l15; if (ae >= e_end) ae = e_end - 1;
                afr = *(const bf16x8*)&ea_perm[(size_t)ae * ED + quad * 8];
            }
            // output rows of C layout: edge = ebase + quad*4 + r
            int srcr[4], dstr[4];
            #pragma unroll
            for (int r = 0; r < 4; ++r) {
                int er = ebase + quad * 4 + r; if (er >= e_end) er = e_end - 1;
                srcr[r] = src_perm[er];
                dstr[r] = dst_perm[er] - n0;
            }
            // batch the x gathers (16 independent loads in flight)
            float xg[4][4];
            #pragma unroll
            for (int nb = 0; nb < 4; ++nb)
                #pragma unroll
                for (int r = 0; r < 4; ++r)
                    xg[nb][r] = ld1(&x[(size_t)srcr[r] * CIN + colw + nb * 16 + l15]);
            // MFMA edge-MLP + epilogue
            #pragma unroll
            for (int nb = 0; nb < 4; ++nb) {
                f32x4 c = {bev[nb], bev[nb], bev[nb], bev[nb]};
                c = __builtin_amdgcn_mfma_f32_16x16x32_bf16(afr, bfr[nb], c, 0, 0, 0);
                #pragma unroll
                for (int r = 0; r < 4; ++r) {
                    if (ebase + quad * 4 + r < e_end) {
                        const float m = fmaxf(c[r] + xg[nb][r], 0.f);
                        atomicAdd(&sacc[dstr[r] * LDSROW + colw + nb * 16 + l15], m);
                    }
                }
            }
        }
    }
    __syncthreads();

    // write back bf16 (coalesced)
    for (int i = tid * 4; i < NPB * CIN; i += 1024) {
        const int node = i / CIN, col = i % CIN;
        st4(&agg[(size_t)n0 * CIN + i], *(const float4*)&sacc[node * LDSROW + col]);
    }
}

// ===========================================================================
// MFMA GEMM for conv layers: C[M,256] = relu(A[M,K] @ Wt[256,K]^T + bias)
// A bf16 row-major, Wt bf16 [N,K] (pre-transposed), C bf16, fp32 accumulate.
// 128x128 tile, BK=32, 256 threads = 4 waves (each 64x64), 16x16x32 MFMA.
// ===========================================================================
template<int K>
__global__ __launch_bounds__(256)
void gemm_mfma(const bf16* __restrict__ A, const bf16* __restrict__ Wt,
               const float* __restrict__ bias, bf16* __restrict__ C, int M)
{
    constexpr int LDT = 40;                 // padded LDS row stride (bf16)
    __shared__ short As[128 * LDT];
    __shared__ short Bs[128 * LDT];
    const int tid  = threadIdx.x;
    const int bm   = blockIdx.y * 128;
    const int bn   = blockIdx.x * 128;      // 0 or 128 (N = 256)
    const int lane = tid & 63;
    const int wave = tid >> 6;
    const int wr   = (wave >> 1) * 64;      // wave row offset in tile
    const int wc   = (wave & 1) * 64;       // wave col offset
    const int l15  = lane & 15;
    const int quad = lane >> 4;

    f32x4 acc[4][4];
    #pragma unroll
    for (int i = 0; i < 4; ++i)
        #pragma unroll
        for (int j = 0; j < 4; ++j)
            acc[i][j] = (f32x4){0.f, 0.f, 0.f, 0.f};

    for (int k0 = 0; k0 < K; k0 += 32) {
        #pragma unroll
        for (int c = tid; c < 512; c += 256) {
            const int row = c >> 2, part = c & 3;
            int ar = bm + row; if (ar >= M) ar = M - 1;   // clamp; rows discarded at store
            *(ulonglong2*)&As[row * LDT + part * 8] =
                *(const ulonglong2*)&A[(size_t)ar * K + k0 + part * 8];
            *(ulonglong2*)&Bs[row * LDT + part * 8] =
                *(const ulonglong2*)&Wt[(size_t)(bn + row) * K + k0 + part * 8];
        }
        __syncthreads();

        bf16x8 af[4], bfr[4];
        #pragma unroll
        for (int i = 0; i < 4; ++i) {
            af[i]  = *(const bf16x8*)&As[(wr + i * 16 + l15) * LDT + quad * 8];
            bfr[i] = *(const bf16x8*)&Bs[(wc + i * 16 + l15) * LDT + quad * 8];
        }
        #pragma unroll
        for (int mi = 0; mi < 4; ++mi)
            #pragma unroll
            for (int ni = 0; ni < 4; ++ni)
                acc[mi][ni] = __builtin_amdgcn_mfma_f32_16x16x32_bf16(
                                  af[mi], bfr[ni], acc[mi][ni], 0, 0, 0);
        __syncthreads();
    }

    // epilogue: D row = quad*4+reg, col = lane&15 (m89-verified C/D layout)
    float bv[4];
    #pragma unroll
    for (int ni = 0; ni < 4; ++ni)
        bv[ni] = bias[bn + wc + ni * 16 + l15];
    #pragma unroll
    for (int mi = 0; mi < 4; ++mi) {
        const int row0 = bm + wr + mi * 16 + quad * 4;
        #pragma unroll
        for (int r = 0; r < 4; ++r) {
            const int row = row0 + r;
            if (row < M) {
                #pragma unroll
                for (int ni = 0; ni < 4; ++ni) {
                    float v = acc[mi][ni][r] + bv[ni];
                    v = fmaxf(v, 0.f);
                    C[(size_t)row * 256 + bn + wc + ni * 16 + l15] = __float2bfloat16(v);
                }
            }
        }
    }
}

// ---------------------------------------------------------------------------
// fp32 GEMM (dense head only): C = (relu?)(A @ W + bias)
// ---------------------------------------------------------------------------
template<bool RELU, typename InT, typename OutT>
__global__ __launch_bounds__(256)
void gemm_rk(const InT* __restrict__ A, const float* __restrict__ W,
             const float* __restrict__ bias, OutT* __restrict__ C,
             int M, int N, int K)
{
    __shared__ float Asm[16][64];
    __shared__ float Wsm[16][64];
    const int bm = blockIdx.y * 64;
    const int bn = blockIdx.x * 64;
    const int tid = threadIdx.x;
    const int tx = tid & 15, ty = tid >> 4;
    const int ar = tid >> 2, ac = (tid & 3) * 4;
    const int wrr = tid >> 4, wcc = (tid & 15) * 4;

    float acc[4][4] = {};

    for (int k0 = 0; k0 < K; k0 += 16) {
        float4 av = make_float4(0.f, 0.f, 0.f, 0.f);
        if (bm + ar < M)
            av = ld4(A + (size_t)(bm + ar) * K + k0 + ac);
        Asm[ac + 0][ar] = av.x; Asm[ac + 1][ar] = av.y;
        Asm[ac + 2][ar] = av.z; Asm[ac + 3][ar] = av.w;

        float4 wv = make_float4(0.f, 0.f, 0.f, 0.f);
        if (bn + wcc < N)
            wv = *(const float4*)(W + (size_t)(k0 + wrr) * N + bn + wcc);
        *(float4*)&Wsm[wrr][wcc] = wv;
        __syncthreads();

        #pragma unroll
        for (int k = 0; k < 16; ++k) {
            const float4 a4 = *(const float4*)&Asm[k][ty * 4];
            const float4 b4 = *(const float4*)&Wsm[k][tx * 4];
            const float aa[4] = {a4.x, a4.y, a4.z, a4.w};
            const float bb[4] = {b4.x, b4.y, b4.z, b4.w};
            #pragma unroll
            for (int i = 0; i < 4; ++i)
                #pragma unroll
                for (int j = 0; j < 4; ++j)
                    acc[i][j] += aa[i] * bb[j];
        }
        __syncthreads();
    }

    float bvals[4];
    #pragma unroll
    for (int j = 0; j < 4; ++j) {
        const int col = bn + tx * 4 + j;
        bvals[j] = (col < N) ? bias[col] : 0.f;
    }
    #pragma unroll
    for (int i = 0; i < 4; ++i) {
        const int row = bm + ty * 4 + i;
        if (row >= M) continue;
        float v[4];
        #pragma unroll
        for (int j = 0; j < 4; ++j) {
            v[j] = acc[i][j] + bvals[j];
            if (RELU) v[j] = fmaxf(v[j], 0.f);
        }
        if (bn + tx * 4 + 3 < N) {
            st4(C + (size_t)row * N + bn + tx * 4, make_float4(v[0], v[1], v[2], v[3]));
        } else {
            #pragma unroll
            for (int j = 0; j < 4; ++j) {
                const int col = bn + tx * 4 + j;
                if (col < N) st1(C + (size_t)row * N + col, v[j]);
            }
        }
    }
}

// ---------------------------------------------------------------------------
// BatchNorm stats + normalize (bf16 H), fp32 accumulate.
// ---------------------------------------------------------------------------
template<typename InT>
__global__ __launch_bounds__(256)
void bn_stats(const InT* __restrict__ h, float* __restrict__ stats, int nodes)
{
    const int c = threadIdx.x;
    size_t n0 = (size_t)blockIdx.x * 128;
    size_t n1 = n0 + 128; if (n1 > (size_t)nodes) n1 = nodes;
    if (n0 >= (size_t)nodes) return;
    float s = 0.f, s2 = 0.f;
    for (size_t n = n0; n < n1; ++n) {
        const float v = ld1(&h[n * 256 + c]);
        s += v; s2 += v * v;
    }
    atomicAdd(&stats[c], s);
    atomicAdd(&stats[256 + c], s2);
}

template<typename T>
__global__ __launch_bounds__(256)
void bn_norm(T* __restrict__ h, const float* __restrict__ stats,
             const float* __restrict__ gamma, const float* __restrict__ beta, int n4)
{
    int i = blockIdx.x * 256 + threadIdx.x;
    const int stride = gridDim.x * 256;
    const float inv = 1.f / (float)NN;
    for (; i < n4; i += stride) {
        const int c = (i * 4) & 255;
        float4 v  = ld4(h + (size_t)i * 4);
        const float4 s  = *(const float4*)&stats[c];
        const float4 s2 = *(const float4*)&stats[256 + c];
        const float4 g  = *(const float4*)&gamma[c];
        const float4 b  = *(const float4*)&beta[c];
        float mu, sc;
        mu = s.x * inv; sc = rsqrtf(s2.x * inv - mu * mu + BN_EPS) * g.x; v.x = (v.x - mu) * sc + b.x;
        mu = s.y * inv; sc = rsqrtf(s2.y * inv - mu * mu + BN_EPS) * g.y; v.y = (v.y - mu) * sc + b.y;
        mu = s.z * inv; sc = rsqrtf(s2.z * inv - mu * mu + BN_EPS) * g.z; v.z = (v.z - mu) * sc + b.z;
        mu = s.w * inv; sc = rsqrtf(s2.w * inv - mu * mu + BN_EPS) * g.w; v.w = (v.w - mu) * sc + b.w;
        st4(h + (size_t)i * 4, v);
    }
}

// ---------------------------------------------------------------------------
// Mean-pool over sorted batch ids.
// ---------------------------------------------------------------------------
template<typename InT>
__global__ __launch_bounds__(256)
void pool_sum(const InT* __restrict__ h, const int* __restrict__ batch,
              float* __restrict__ sums, float* __restrict__ cnts)
{
    const int c = threadIdx.x;
    size_t n0 = (size_t)blockIdx.x * 128;
    size_t n1 = n0 + 128; if (n1 > (size_t)NN) n1 = NN;
    if (n0 >= (size_t)NN) return;
    int cur = batch[n0];
    float s = 0.f, cnt = 0.f;
    for (size_t n = n0; n < n1; ++n) {
        const int b = batch[n];
        if (b != cur) {
            atomicAdd(&sums[(size_t)cur * 256 + c], s);
            if (c == 0) atomicAdd(&cnts[cur], cnt);
            s = 0.f; cnt = 0.f; cur = b;
        }
        s += ld1(&h[n * 256 + c]);
        cnt += 1.f;
    }
    atomicAdd(&sums[(size_t)cur * 256 + c], s);
    if (c == 0) atomicAdd(&cnts[cur], cnt);
}

__global__ __launch_bounds__(256)
void pool_div(float* __restrict__ sums, const float* __restrict__ cnts)
{
    const int i = blockIdx.x * 256 + threadIdx.x;   // NG*256 threads exactly
    const int g = i >> 8;
    sums[i] = sums[i] / fmaxf(cnts[g], 1.f);
}

__global__ __launch_bounds__(256)
void head_out(const float* __restrict__ y, const float* __restrict__ Wo,
              const float* __restrict__ bo, float* __restrict__ out)
{
    const int g = blockIdx.x * 256 + threadIdx.x;
    if (g >= NG) return;
    float s = bo[0];
    #pragma unroll
    for (int k = 0; k < 32; ++k) s += y[g * 32 + k] * Wo[k];
    out[g] = s;
}

__global__ __launch_bounds__(256)
void diag_fill(float* __restrict__ out, int n, float v)
{
    const int i = blockIdx.x * 256 + threadIdx.x;
    if (i < n) out[i] = v;
}

// ---------------------------------------------------------------------------
extern "C" void kernel_launch(void* const* d_in, const int* in_sizes, int n_in,
                              void* d_out, int out_size, void* d_ws, size_t ws_size,
                              hipStream_t stream)
{
    const float* x    = (const float*)d_in[0];
    const int*   ei   = (const int*)d_in[1];
    const int*   batch= (const int*)d_in[2];
    const float* ea   = (const float*)d_in[3];
    const float* We[3] = {(const float*)d_in[4],  (const float*)d_in[10], (const float*)d_in[16]};
    const float* be[3] = {(const float*)d_in[5],  (const float*)d_in[11], (const float*)d_in[17]};
    const float* Wn[3] = {(const float*)d_in[6],  (const float*)d_in[12], (const float*)d_in[18]};
    const float* bnb[3]= {(const float*)d_in[7],  (const float*)d_in[13], (const float*)d_in[19]};
    const float* gm[3] = {(const float*)d_in[8],  (const float*)d_in[14], (const float*)d_in[20]};
    const float* bt[3] = {(const float*)d_in[9],  (const float*)d_in[15], (const float*)d_in[21]};
    const float* Wd0 = (const float*)d_in[22]; const float* bd0 = (const float*)d_in[23];
    const float* Wd1 = (const float*)d_in[24]; const float* bd1 = (const float*)d_in[25];
    const float* Wd2 = (const float*)d_in[26]; const float* bd2 = (const float*)d_in[27];
    const float* Wo  = (const float*)d_in[28]; const float* bo  = (const float*)d_in[29];
    float* out = (float*)d_out;
    float* ws  = (float*)d_ws;

    // ---- workspace layout (float offsets; 16B/32B alignment kept) ----
    bf16*  H        = (bf16*)ws;                  // NN*256 bf16 = 25.6M fl
    bf16*  AGG      = (bf16*)(ws + 25600000);     // NN*256 bf16 = 25.6M fl
    float* st       = ws + 51200000;              // 512 fl
    bf16*  wt0      = (bf16*)(ws + 51200512);     // 128*256 bf16 = 16384 fl
    bf16*  wt1      = wt0 + 32768;                // 256*256 bf16 = 32768 fl
    bf16*  wt2      = wt1 + 65536;                // 256*256 bf16 = 32768 fl
    bf16*  Wb0      = (bf16*)(ws + 51282432);     // 128*32 bf16 = 2048 fl
    bf16*  Wb1      = (bf16*)(ws + 51284480);     // 256*32 bf16 = 4096 fl
    bf16*  Wb2      = (bf16*)(ws + 51288576);     // 256*32 bf16 = 4096 fl
    bf16*  ea_perm  = (bf16*)(ws + 51292672);     // NE*16 bf16 = 6.4M fl
    int*   src_perm = (int*)(ws + 57692672);      // NE
    int*   dst_perm = src_perm + NE;              // NE
    int*   row_ptr  = dst_perm + NE;              // NN+1
    int*   cursor   = row_ptr + (NN + 1);         // NN
    int*   bsum     = cursor + NN;                // SCAN_NBLK
    const size_t NEED = (size_t)(57692672 + NE + NE + (NN + 1) + NN + SCAN_NBLK) * 4;

    if (ws_size < NEED) {
        diag_fill<<<(NG + 255) / 256, 256, 0, stream>>>(out, NG, (float)(ws_size >> 20));
        return;
    }

    // ---- one-time prep: CSR build + fused edge scatter, weight packing ----
    hipMemsetAsync(row_ptr, 0, (size_t)(NN + 1) * 4, stream);
    k_hist<<<1024, 256, 0, stream>>>(ei, row_ptr);
    k_scan_block<<<SCAN_NBLK, 256, 0, stream>>>(row_ptr, bsum);
    k_scan_top<<<1, 256, 0, stream>>>(bsum, SCAN_NBLK);
    k_scan_emit<<<SCAN_NBLK, 256, 0, stream>>>(row_ptr, bsum, row_ptr, cursor);
    k_scatter2<<<1024, 256, 0, stream>>>(ei, ea, cursor, src_perm, dst_perm, ea_perm);
    k_wt<<<(128 * 256 + 255) / 256, 256, 0, stream>>>(Wn[0], wt0, 128, 256);
    k_wt<<<(256 * 256 + 255) / 256, 256, 0, stream>>>(Wn[1], wt1, 256, 256);
    k_wt<<<(256 * 256 + 255) / 256, 256, 0, stream>>>(Wn[2], wt2, 256, 256);
    k_wb<<<2, 256, 0, stream>>>(We[0], Wb0, 128);
    k_wb<<<4, 256, 0, stream>>>(We[1], Wb1, 256);
    k_wb<<<4, 256, 0, stream>>>(We[2], Wb2, 256);

    const dim3 mfma_grid(2, (NN + 127) / 128);    // N=256 -> 2 col-blocks
    const int  agg_grid = NN / NPB;               // 6250 blocks (NN % 32 == 0)

    // ---- layer 0 (cin=128 -> 256), input x fp32 ----
    node_agg5<float, 128><<<agg_grid, 256, 0, stream>>>(x, ea_perm, src_perm, dst_perm, row_ptr, Wb0, be[0], AGG);
    gemm_mfma<128><<<mfma_grid, 256, 0, stream>>>(AGG, wt0, bnb[0], H, NN);
    hipMemsetAsync(st, 0, 512 * 4, stream);
    bn_stats<bf16><<<(NN + 127) / 128, 256, 0, stream>>>(H, st, NN);
    bn_norm<bf16><<<2048, 256, 0, stream>>>(H, st, gm[0], bt[0], NN * 256 / 4);

    // ---- layers 1,2 (256 -> 256), input H bf16 ----
    for (int l = 1; l < 3; ++l) {
        node_agg5<bf16, 256><<<agg_grid, 256, 0, stream>>>(H, ea_perm, src_perm, dst_perm, row_ptr, (l == 1) ? Wb1 : Wb2, be[l], AGG);
        gemm_mfma<256><<<mfma_grid, 256, 0, stream>>>(AGG, (l == 1) ? wt1 : wt2, bnb[l], H, NN);
        hipMemsetAsync(st, 0, 512 * 4, stream);
        bn_stats<bf16><<<(NN + 127) / 128, 256, 0, stream>>>(H, st, NN);
        bn_norm<bf16><<<2048, 256, 0, stream>>>(H, st, gm[l], bt[l], NN * 256 / 4);
    }

    // ---- head scratch overlays AGG (dead after last conv GEMM) ----
    float* poolb = (float*)AGG;           // NG*256 = 1,024,000 fl
    float* cnts  = poolb + 1024000;       // NG
    float* y1    = poolb + 1028000;       // NG*512
    float* y2    = poolb + 3076000;       // NG*128
    float* y3    = poolb + 3588000;       // NG*32

    hipMemsetAsync(poolb, 0, (size_t)NG * 256 * 4, stream);
    hipMemsetAsync(cnts, 0, (size_t)NG * 4, stream);
    pool_sum<bf16><<<(NN + 127) / 128, 256, 0, stream>>>(H, batch, poolb, cnts);
    pool_div<<<NG, 256, 0, stream>>>(poolb, cnts);

    // ---- dense head (fp32) ----
    gemm_rk<true, float, float><<<dim3(8, (NG + 63) / 64), 256, 0, stream>>>(poolb, Wd0, bd0, y1, NG, 512, 256);
    gemm_rk<true, float, float><<<dim3(2, (NG + 63) / 64), 256, 0, stream>>>(y1, Wd1, bd1, y2, NG, 128, 512);
    gemm_rk<true, float, float><<<dim3(1, (NG + 63) / 64), 256, 0, stream>>>(y2, Wd2, bd2, y3, NG, 32, 128);
    head_out<<<(NG + 255) / 256, 256, 0, stream>>>(y3, Wo, bo, out);
}